// Round 13
// baseline (56.651 us; speedup 1.0000x reference)
//
#include <hip/hip_runtime.h>
#include <hip/hip_bf16.h>

// Sliding-window attention, B=1 H=16 S=8192 D=64, window +/- w (w=256 at bench).
// fp32 in/out; bf16 MFMA, fp32 accum, static softmax in exp2 domain.
// R13: R12 two-phase (prepack -> gl_lds main) with QT=256: each wave owns 32
//      q-rows (2 rb), so every K/V ds_read_b128 feeds 2x the MFMA. LDS port
//      (~55% of main-kernel cycles, reads identical across waves) halves per
//      q-row; stagings drop 10240->6144. Grid 512, NW=8, LDS 32KB unchanged.

#define NH  16
#define SEQ 8192
#define HD  64
#define QT  256      // q rows per workgroup
#define NW  8        // waves per workgroup (32 q-rows each)
#define KVB 64       // keys per iteration
#define NEGV -1e30f
#define NTILE (SEQ / KVB)              // 128 tiles per head
#define TILE_ELEMS (KVB * HD)          // 4096 bf16 = 8KB per tile image

typedef __bf16 bf16x8 __attribute__((ext_vector_type(8)));
typedef float  f32x4  __attribute__((ext_vector_type(4)));

// K-tile row permutation (must match compute kernel's read pattern)
__device__ __forceinline__ int prow_of(int key) {
    return ((key >> 2) & 1) * 32 + ((key >> 5) & 1) * 16
         + ((key >> 3) & 3) * 4  + (key & 3);
}

// ============================ kernel 1: prepack ============================
// grid: 2*NH*NTILE blocks of 512. First half: K tiles; second half: V tiles.
__global__ __launch_bounds__(512) void prepack(
    const float* __restrict__ K, const float* __restrict__ V,
    __bf16* __restrict__ kpp, __bf16* __restrict__ vpp)
{
    const int b   = blockIdx.x;
    const int isV = b >= NH * NTILE;
    const int t   = isV ? b - NH * NTILE : b;     // h*NTILE + tile
    const int tid = threadIdx.x;

    const float* src = (isV ? V : K) + (size_t)t * TILE_ELEMS; // 64 keys x 64 d
    __bf16*      dst = (isV ? vpp : kpp) + (size_t)t * TILE_ELEMS;

    if (!isV) {
        // K: row key -> physical row prow(key), d-chunk XOR swizzle
        const int key = tid >> 3, c = tid & 7;
        const float* s = src + key * HD + c * 8;
        float4 a = *(const float4*)s;
        float4 q = *(const float4*)(s + 4);
        bf16x8 o;
        o[0]=(__bf16)a.x; o[1]=(__bf16)a.y; o[2]=(__bf16)a.z; o[3]=(__bf16)a.w;
        o[4]=(__bf16)q.x; o[5]=(__bf16)q.y; o[6]=(__bf16)q.z; o[7]=(__bf16)q.w;
        const int pr = prow_of(key);
        *(bf16x8*)&dst[pr * 64 + ((c * 8) ^ ((pr & 7) << 3))] = o;
    } else {
        // V: transpose via LDS (coalesced read + coalesced write)
        __shared__ float Vl[64][65];
        const int key = tid >> 3, c = tid & 7;
        const float* s = src + key * HD + c * 8;
        float4 a = *(const float4*)s;
        float4 q = *(const float4*)(s + 4);
        Vl[key][c*8+0]=a.x; Vl[key][c*8+1]=a.y; Vl[key][c*8+2]=a.z; Vl[key][c*8+3]=a.w;
        Vl[key][c*8+4]=q.x; Vl[key][c*8+5]=q.y; Vl[key][c*8+6]=q.z; Vl[key][c*8+7]=q.w;
        __syncthreads();
        const int vd = tid >> 3, kc = tid & 7;
        bf16x8 o;
#pragma unroll
        for (int j = 0; j < 8; ++j) o[j] = (__bf16)Vl[kc*8 + j][vd];
        *(bf16x8*)&dst[vd * 64 + ((kc * 8) ^ ((vd & 7) << 3))] = o;
    }
}

// ========================= kernel 2: main (gl_lds) =========================
#define GLOAD_LDS16(G, L)                                                      \
    __builtin_amdgcn_global_load_lds(                                          \
        (const __attribute__((address_space(1))) void*)(G),                    \
        (__attribute__((address_space(3))) void*)(L), 16, 0, 0)

__global__ __launch_bounds__(512) void swa_fwd(
    const float* __restrict__ Q, const __bf16* __restrict__ kpp,
    const __bf16* __restrict__ vpp, float* __restrict__ O,
    const int* __restrict__ wsz)
{
    const int w    = wsz[0];
    const int w2   = 2 * w;

    // XCD-aware decode (grid 512 = 8 XCD x 64): each XCD owns heads
    // {2*xcd, 2*xcd+1}; 32 q-blocks per head
    const int lin = blockIdx.x;
    const int xcd = lin & 7;
    const int i2  = lin >> 3;            // 0..63
    const int h   = 2 * xcd + (i2 >> 5); // 0..15
    const int q0  = (i2 & 31) * QT;

    const int tid  = threadIdx.x;
    const int lane = tid & 63;
    const int wv   = tid >> 6;
    const int l15  = lane & 15;
    const int g    = lane >> 4;

    const float* Qh = Q + (size_t)h * SEQ * HD;
    float*       Oh = O + (size_t)h * SEQ * HD;

    // LDS tile images (prepacked layout; double-buffered); 32KB total
    __shared__ __align__(16) __bf16 Ks[2][TILE_ELEMS];
    __shared__ __align__(16) __bf16 Vt[2][TILE_ELEMS];

    // Q fragments (B-operand: col=q=l15, k=d=g*8+j); scale into log2 domain
    const float qscale = 0.125f * 1.44269504f;
    bf16x8 qf[2][2];
#pragma unroll
    for (int rb = 0; rb < 2; ++rb)
#pragma unroll
        for (int ks = 0; ks < 2; ++ks) {
            const float* src = Qh + (size_t)(q0 + wv*32 + rb*16 + l15) * HD + ks*32 + g*8;
            float4 a = *(const float4*)src;
            float4 b = *(const float4*)(src + 4);
            bf16x8 t;
            t[0] = (__bf16)(a.x * qscale); t[1] = (__bf16)(a.y * qscale);
            t[2] = (__bf16)(a.z * qscale); t[3] = (__bf16)(a.w * qscale);
            t[4] = (__bf16)(b.x * qscale); t[5] = (__bf16)(b.y * qscale);
            t[6] = (__bf16)(b.z * qscale); t[7] = (__bf16)(b.w * qscale);
            qf[rb][ks] = t;
        }

    f32x4 acc[2][4];
    float lrp[2] = {0.f, 0.f};
#pragma unroll
    for (int rb = 0; rb < 2; ++rb)
#pragma unroll
        for (int db = 0; db < 4; ++db)
            acc[rb][db] = f32x4{0.f, 0.f, 0.f, 0.f};

    int kv_lo = q0 - w; if (kv_lo < 0) kv_lo = 0; kv_lo &= ~(KVB - 1);
    int kv_hi = q0 + QT + w; if (kv_hi > SEQ) kv_hi = SEQ;
    kv_hi = (kv_hi + KVB - 1) & ~(KVB - 1);
    const int nT = (kv_hi - kv_lo) / KVB;

    const int rw0 = q0 + wv * 32;   // this wave's first q row

    // staging: wave wv DMAs chunk wv (1KB) of the K image and of the V image
    const size_t headTileBase = (size_t)h * NTILE * TILE_ELEMS;
    const int    chunkOff     = wv * 512 + lane * 8;   // elems; 16B per lane

#define STAGE_TILE(TI, BUF)                                                    \
    {                                                                          \
        const size_t tb = headTileBase + (size_t)(TI) * TILE_ELEMS;            \
        GLOAD_LDS16(kpp + tb + chunkOff, &Ks[BUF][wv * 512]);                  \
        GLOAD_LDS16(vpp + tb + chunkOff, &Vt[BUF][wv * 512]);                  \
    }

#define WG_BARRIER()                                                           \
    asm volatile("s_waitcnt vmcnt(0) lgkmcnt(0)" ::: "memory");                \
    __builtin_amdgcn_sched_barrier(0);                                         \
    __builtin_amdgcn_s_barrier();                                              \
    __builtin_amdgcn_sched_barrier(0);

    // prologue: tile 0
    STAGE_TILE(kv_lo >> 6, 0);
    WG_BARRIER();

    for (int it = 0; it < nT; ++it) {
        const int kb = kv_lo + it * KVB;
        const __bf16* Kb = &Ks[it & 1][0];
        const __bf16* Vb = &Vt[it & 1][0];

        // round head: DMA next tile; completes under this round's compute
        if (it + 1 < nT) STAGE_TILE((kb >> 6) + 1, (it + 1) & 1);

        // this wave's 32 rows vs this 64-key tile
        if (kb <= rw0 + 31 + w && kb + KVB - 1 >= rw0 - w) {
            const int sw = (l15 & 7) << 3;

            // ---- S^T = K x Q: each K-frag read feeds BOTH rb (LDS dedup).
            //      st[rb][t][r] = S[key=a(t,g,r)][q = rb half + l15] ----
            f32x4 st[2][4];
#pragma unroll
            for (int t = 0; t < 4; ++t) {
                bf16x8 kf0 = *(const bf16x8*)&Kb[(t*16 + l15)*64 + ((     g*8) ^ sw)];
                bf16x8 kf1 = *(const bf16x8*)&Kb[(t*16 + l15)*64 + ((32 + g*8) ^ sw)];
                f32x4 z0{0.f,0.f,0.f,0.f}, z1{0.f,0.f,0.f,0.f};
                z0       = __builtin_amdgcn_mfma_f32_16x16x32_bf16(kf0, qf[0][0], z0, 0,0,0);
                st[0][t] = __builtin_amdgcn_mfma_f32_16x16x32_bf16(kf1, qf[0][1], z0, 0,0,0);
                z1       = __builtin_amdgcn_mfma_f32_16x16x32_bf16(kf0, qf[1][0], z1, 0,0,0);
                st[1][t] = __builtin_amdgcn_mfma_f32_16x16x32_bf16(kf1, qf[1][1], z1, 0,0,0);
            }

            // mask (only when the 32-row x 64-key block isn't fully in band);
            // fully-masked rows give p=0 -> contribute 0 to acc and l
            const bool full = (kb + KVB-1 - rw0 <= w) && (kb - (rw0 + 31) >= -w);
            if (!full) {
#pragma unroll
                for (int rb = 0; rb < 2; ++rb) {
                    const int relb = kb + g*8 + w - (rw0 + rb*16) - l15;
#pragma unroll
                    for (int t = 0; t < 4; ++t)
#pragma unroll
                        for (int r = 0; r < 4; ++r)
                            if ((unsigned)(relb + (t&1)*32 + (t>>1)*4 + r) > (unsigned)w2)
                                st[rb][t][r] = NEGV;
                }
            }

            // p = exp2(min(s,80)); static softmax; per-lane partial sums
            float p[2][4][4];
#pragma unroll
            for (int rb = 0; rb < 2; ++rb) {
#pragma unroll
                for (int t = 0; t < 4; ++t)
#pragma unroll
                    for (int r = 0; r < 4; ++r)
                        p[rb][t][r] = __builtin_amdgcn_exp2f(fminf(st[rb][t][r], 80.f));
                float s01 = (p[rb][0][0] + p[rb][0][1]) + (p[rb][0][2] + p[rb][0][3]);
                float s23 = (p[rb][1][0] + p[rb][1][1]) + (p[rb][1][2] + p[rb][1][3]);
                float s45 = (p[rb][2][0] + p[rb][2][1]) + (p[rb][2][2] + p[rb][2][3]);
                float s67 = (p[rb][3][0] + p[rb][3][1]) + (p[rb][3][2] + p[rb][3][3]);
                lrp[rb] += (s01 + s23) + (s45 + s67);
            }

            // PV: each V-frag read feeds BOTH rb.
            // pf[rb][kh] = {p[rb][kh][0..3], p[rb][kh+2][0..3]}
#pragma unroll
            for (int kh = 0; kh < 2; ++kh) {
                bf16x8 pf0, pf1;
                pf0[0]=(__bf16)p[0][kh][0];   pf0[1]=(__bf16)p[0][kh][1];
                pf0[2]=(__bf16)p[0][kh][2];   pf0[3]=(__bf16)p[0][kh][3];
                pf0[4]=(__bf16)p[0][kh+2][0]; pf0[5]=(__bf16)p[0][kh+2][1];
                pf0[6]=(__bf16)p[0][kh+2][2]; pf0[7]=(__bf16)p[0][kh+2][3];
                pf1[0]=(__bf16)p[1][kh][0];   pf1[1]=(__bf16)p[1][kh][1];
                pf1[2]=(__bf16)p[1][kh][2];   pf1[3]=(__bf16)p[1][kh][3];
                pf1[4]=(__bf16)p[1][kh+2][0]; pf1[5]=(__bf16)p[1][kh+2][1];
                pf1[6]=(__bf16)p[1][kh+2][2]; pf1[7]=(__bf16)p[1][kh+2][3];
#pragma unroll
                for (int db = 0; db < 4; ++db) {
                    bf16x8 vfr = *(const bf16x8*)&Vb[(db*16 + l15)*64 + ((kh*32 + g*8) ^ sw)];
                    acc[0][db] = __builtin_amdgcn_mfma_f32_16x16x32_bf16(pf0, vfr, acc[0][db], 0,0,0);
                    acc[1][db] = __builtin_amdgcn_mfma_f32_16x16x32_bf16(pf1, vfr, acc[1][db], 0,0,0);
                }
            }
        }

        WG_BARRIER();
    }

    // epilogue: g-reduce l, normalize, store (per rb)
#pragma unroll
    for (int rb = 0; rb < 2; ++rb) {
        float lr = lrp[rb];
        lr += __shfl_xor(lr, 16);
        lr += __shfl_xor(lr, 32);
        const float il = 1.0f / lr;
        float inv[4];
#pragma unroll
        for (int r = 0; r < 4; ++r) inv[r] = __shfl(il, g*4 + r);
#pragma unroll
        for (int db = 0; db < 4; ++db)
#pragma unroll
            for (int r = 0; r < 4; ++r) {
                const int row = rw0 + rb*16 + g*4 + r;
                Oh[(size_t)row * HD + db*16 + l15] = acc[rb][db][r] * inv[r];
            }
    }
}

// ===================== fallback (R10, fp32-staged, QT=128) =================
__global__ __launch_bounds__(512) void swa_fwd_fb(
    const float* __restrict__ Q, const float* __restrict__ K,
    const float* __restrict__ V, float* __restrict__ O,
    const int* __restrict__ wsz)
{
    const int w    = wsz[0];
    const int w2   = 2 * w;
    const int lin = blockIdx.x;
    const int xcd = lin & 7;
    const int i2  = lin >> 3;
    const int h   = 2 * xcd + (i2 >> 6);
    const int q0  = (i2 & 63) * 128;
    const int tid  = threadIdx.x;
    const int lane = tid & 63;
    const int wv   = tid >> 6;
    const int l15  = lane & 15;
    const int g    = lane >> 4;
    const size_t hoff = (size_t)h * SEQ * HD;
    const float* Qh = Q + hoff;
    const float* Kh = K + hoff;
    const float* Vh = V + hoff;
    float*       Oh = O + hoff;
    __shared__ __align__(16) __bf16 Ks[2][KVB * 64];
    __shared__ __align__(16) __bf16 Vt[2][64 * 64];
    const float qscale = 0.125f * 1.44269504f;
    const int   qrow   = q0 + wv * 16 + l15;
    bf16x8 qf[2];
#pragma unroll
    for (int ks = 0; ks < 2; ++ks) {
        const float* src = Qh + (size_t)qrow * HD + ks*32 + g*8;
        float4 a = *(const float4*)src;
        float4 b = *(const float4*)(src + 4);
        bf16x8 t;
        t[0] = (__bf16)(a.x * qscale); t[1] = (__bf16)(a.y * qscale);
        t[2] = (__bf16)(a.z * qscale); t[3] = (__bf16)(a.w * qscale);
        t[4] = (__bf16)(b.x * qscale); t[5] = (__bf16)(b.y * qscale);
        t[6] = (__bf16)(b.z * qscale); t[7] = (__bf16)(b.w * qscale);
        qf[ks] = t;
    }
    f32x4 acc[4];
    float lrp = 0.f;
#pragma unroll
    for (int db = 0; db < 4; ++db) acc[db] = f32x4{0.f, 0.f, 0.f, 0.f};
    int kv_lo = q0 - w; if (kv_lo < 0) kv_lo = 0; kv_lo &= ~(KVB - 1);
    int kv_hi = q0 + 128 + w; if (kv_hi > SEQ) kv_hi = SEQ;
    kv_hi = (kv_hi + KVB - 1) & ~(KVB - 1);
    const int nT = (kv_hi - kv_lo) / KVB;
    const int rw0 = q0 + wv * 16;
    const int kkey = tid >> 3, kd8 = (tid & 7) * 8;
    const int prow = prow_of(kkey);
    const int swk  = (prow & 7) << 3;
    const int vd   = tid & 63, vk0 = (tid >> 6) * 8;
    const int swv  = (vd & 7) << 3;
    float4 kpa, kpb;
    float  vp[8];
#define ISSUE_LOADS_FB(KB)                                                     \
    {                                                                          \
        const float* ksrc = Kh + (size_t)((KB) + kkey) * HD + kd8;             \
        kpa = *(const float4*)ksrc;                                            \
        kpb = *(const float4*)(ksrc + 4);                                      \
        const float* vsrc = Vh + (size_t)((KB) + vk0) * HD + vd;               \
        _Pragma("unroll")                                                      \
        for (int j = 0; j < 8; ++j) vp[j] = vsrc[j * HD];                      \
    }
#define CVT_STORE_FB(BUF)                                                      \
    {                                                                          \
        bf16x8 tk;                                                             \
        tk[0] = (__bf16)kpa.x; tk[1] = (__bf16)kpa.y;                          \
        tk[2] = (__bf16)kpa.z; tk[3] = (__bf16)kpa.w;                          \
        tk[4] = (__bf16)kpb.x; tk[5] = (__bf16)kpb.y;                          \
        tk[6] = (__bf16)kpb.z; tk[7] = (__bf16)kpb.w;                          \
        *(bf16x8*)&Ks[BUF][prow*64 + (kd8 ^ swk)] = tk;                        \
        bf16x8 tv;                                                             \
        _Pragma("unroll")                                                      \
        for (int j = 0; j < 8; ++j) tv[j] = (__bf16)vp[j];                     \
        *(bf16x8*)&Vt[BUF][vd*64 + (vk0 ^ swv)] = tv;                          \
    }
#define WG_BARRIER_FB()                                                        \
    asm volatile("s_waitcnt lgkmcnt(0)" ::: "memory");                         \
    __builtin_amdgcn_sched_barrier(0);                                         \
    __builtin_amdgcn_s_barrier();                                              \
    __builtin_amdgcn_sched_barrier(0);
    ISSUE_LOADS_FB(kv_lo);
    CVT_STORE_FB(0);
    if (nT > 1) ISSUE_LOADS_FB(kv_lo + KVB);
    WG_BARRIER_FB();
    for (int it = 0; it < nT; ++it) {
        const int kb = kv_lo + it * KVB;
        const __bf16* Kb = &Ks[it & 1][0];
        const __bf16* Vb = &Vt[it & 1][0];
        if (kb <= rw0 + 15 + w && kb + KVB - 1 >= rw0 - w) {
            const int sw = (l15 & 7) << 3;
            f32x4 st[4];
#pragma unroll
            for (int t = 0; t < 4; ++t) {
                bf16x8 kf0 = *(const bf16x8*)&Kb[(t*16 + l15)*64 + ((     g*8) ^ sw)];
                bf16x8 kf1 = *(const bf16x8*)&Kb[(t*16 + l15)*64 + ((32 + g*8) ^ sw)];
                f32x4 z{0.f, 0.f, 0.f, 0.f};
                z     = __builtin_amdgcn_mfma_f32_16x16x32_bf16(kf0, qf[0], z, 0,0,0);
                st[t] = __builtin_amdgcn_mfma_f32_16x16x32_bf16(kf1, qf[1], z, 0,0,0);
            }
            const bool full = (kb + KVB-1 - rw0 <= w) && (kb - (rw0 + 15) >= -w);
            if (!full) {
                const int relb = kb + g*8 + w - rw0 - l15;
#pragma unroll
                for (int t = 0; t < 4; ++t)
#pragma unroll
                    for (int r = 0; r < 4; ++r)
                        if ((unsigned)(relb + (t&1)*32 + (t>>1)*4 + r) > (unsigned)w2)
                            st[t][r] = NEGV;
            }
            float p[4][4];
#pragma unroll
            for (int t = 0; t < 4; ++t)
#pragma unroll
                for (int r = 0; r < 4; ++r)
                    p[t][r] = __builtin_amdgcn_exp2f(fminf(st[t][r], 80.f));
            float s01 = (p[0][0] + p[0][1]) + (p[0][2] + p[0][3]);
            float s23 = (p[1][0] + p[1][1]) + (p[1][2] + p[1][3]);
            float s45 = (p[2][0] + p[2][1]) + (p[2][2] + p[2][3]);
            float s67 = (p[3][0] + p[3][1]) + (p[3][2] + p[3][3]);
            lrp += (s01 + s23) + (s45 + s67);
#pragma unroll
            for (int kh = 0; kh < 2; ++kh) {
                bf16x8 pf;
                pf[0] = (__bf16)p[kh][0];   pf[1] = (__bf16)p[kh][1];
                pf[2] = (__bf16)p[kh][2];   pf[3] = (__bf16)p[kh][3];
                pf[4] = (__bf16)p[kh+2][0]; pf[5] = (__bf16)p[kh+2][1];
                pf[6] = (__bf16)p[kh+2][2]; pf[7] = (__bf16)p[kh+2][3];
#pragma unroll
                for (int db = 0; db < 4; ++db) {
                    bf16x8 vfr = *(const bf16x8*)&Vb[(db*16 + l15)*64 + ((kh*32 + g*8) ^ sw)];
                    acc[db] = __builtin_amdgcn_mfma_f32_16x16x32_bf16(pf, vfr, acc[db], 0,0,0);
                }
            }
        }
        if (it + 1 < nT) {
            CVT_STORE_FB((it + 1) & 1);
            if (it + 2 < nT) ISSUE_LOADS_FB(kb + 2 * KVB);
        }
        WG_BARRIER_FB();
    }
    float lr = lrp;
    lr += __shfl_xor(lr, 16);
    lr += __shfl_xor(lr, 32);
    const float il = 1.0f / lr;
    float inv[4];
#pragma unroll
    for (int r = 0; r < 4; ++r) inv[r] = __shfl(il, g*4 + r);
#pragma unroll
    for (int db = 0; db < 4; ++db)
#pragma unroll
        for (int r = 0; r < 4; ++r) {
            const int row = rw0 + g*4 + r;
            Oh[(size_t)row * HD + db*16 + l15] = acc[db][r] * inv[r];
        }
}

extern "C" void kernel_launch(void* const* d_in, const int* in_sizes, int n_in,
                              void* d_out, int out_size, void* d_ws, size_t ws_size,
                              hipStream_t stream) {
    const float* Q   = (const float*)d_in[0];
    const float* K   = (const float*)d_in[1];
    const float* V   = (const float*)d_in[2];
    const int*   wsz = (const int*)d_in[4];   // window_size (d_in[3]=batch_size unused)
    float* O = (float*)d_out;

    const size_t imgBytes = (size_t)NH * NTILE * TILE_ELEMS * sizeof(__bf16); // 16.78MB
    if (ws_size >= 2 * imgBytes) {
        __bf16* kpp = (__bf16*)d_ws;
        __bf16* vpp = (__bf16*)((char*)d_ws + imgBytes);
        prepack<<<dim3(2 * NH * NTILE), dim3(512), 0, stream>>>(K, V, kpp, vpp);
        swa_fwd<<<dim3((SEQ / QT) * NH), dim3(512), 0, stream>>>(Q, kpp, vpp, O, wsz);
    } else {
        swa_fwd_fb<<<dim3((SEQ / 128) * NH), dim3(512), 0, stream>>>(Q, K, V, O, wsz);
    }
}

// Round 14
// 55.947 us; speedup vs baseline: 1.0126x; 1.0126x over previous
//
#include <hip/hip_runtime.h>
#include <hip/hip_bf16.h>

// Sliding-window attention, B=1 H=16 S=8192 D=64, window +/- w (w=256 at bench).
// fp32 in/out; bf16 MFMA, fp32 accum, static softmax in exp2 domain.
// R14: ZERO-SYNC main kernel. Prepack emits K/V tiles in per-lane MFMA
//      fragment order (16B/lane/frag, key-permutation baked in); main loads
//      fragments straight into VGPRs from L2 (no LDS, no barriers, no
//      staging, no cross-wave coupling). Each wave iterates only its private
//      kv range; K reg-double-buffered, V covered by QK+softmax latency.

#define NH  16
#define SEQ 8192
#define HD  64
#define QT  256      // q rows per workgroup (32 per wave)
#define NW  8
#define KVB 64       // keys per tile
#define NEGV -1e30f
#define NTILE (SEQ / KVB)              // 128 tiles per head
#define TILE_ELEMS (KVB * HD)          // 4096 bf16 = 8KB per tile
#define TILE_U4    (TILE_ELEMS / 8)    // 512 uint4 per tile

typedef __bf16 bf16x8 __attribute__((ext_vector_type(8)));
typedef float  f32x4  __attribute__((ext_vector_type(4)));

// ============================ kernel 1: prepack ============================
// Fragment layouts (16B units, frag f, lane l):
//  K (f = t*2+ks):  holds K[key = (t&1)*32 + ((l&15)>>2)*8 + (t>>1)*4 + (l&3)]
//                        [d = ks*32 + (l>>4)*8 + j]      (A-frag of mfma(K,Q))
//  V (f = kh*4+db): holds V[key = kh*32 + (l>>4)*8 + j][d = db*16 + (l&15)]
//                                                       (B-frag of mfma(P,V))
__global__ __launch_bounds__(512) void prepack(
    const float* __restrict__ K, const float* __restrict__ V,
    __bf16* __restrict__ kpp, __bf16* __restrict__ vpp)
{
    const int b   = blockIdx.x;
    const int isV = b >= NH * NTILE;
    const int t0  = isV ? b - NH * NTILE : b;
    const int tid = threadIdx.x;

    const float* src = (isV ? V : K) + (size_t)t0 * TILE_ELEMS;
    __bf16*      dst = (isV ? vpp : kpp) + (size_t)t0 * TILE_ELEMS;

    __shared__ float Tl[64][65];
    {
        const int key = tid >> 3, c = tid & 7;
        const float* s = src + key * HD + c * 8;
        float4 a = *(const float4*)s;
        float4 q = *(const float4*)(s + 4);
        Tl[key][c*8+0]=a.x; Tl[key][c*8+1]=a.y; Tl[key][c*8+2]=a.z; Tl[key][c*8+3]=a.w;
        Tl[key][c*8+4]=q.x; Tl[key][c*8+5]=q.y; Tl[key][c*8+6]=q.z; Tl[key][c*8+7]=q.w;
    }
    __syncthreads();

    const int f = tid >> 6, l = tid & 63, i = l & 15, gg = l >> 4;
    bf16x8 o;
    if (!isV) {
        const int t = f >> 1, ks = f & 1;
        const int kk = (t & 1) * 32 + (i >> 2) * 8 + (t >> 1) * 4 + (i & 3);
        const int d0 = ks * 32 + gg * 8;
#pragma unroll
        for (int j = 0; j < 8; ++j) o[j] = (__bf16)Tl[kk][d0 + j];
    } else {
        const int kh = f >> 2, db = f & 3;
        const int d  = db * 16 + i;
        const int k0 = kh * 32 + gg * 8;
#pragma unroll
        for (int j = 0; j < 8; ++j) o[j] = (__bf16)Tl[k0 + j][d];
    }
    *(bf16x8*)&dst[tid * 8] = o;
}

// ====================== kernel 2: main (zero-sync) =========================
__global__ __launch_bounds__(512) void swa_fwd(
    const float* __restrict__ Q, const __bf16* __restrict__ kpp,
    const __bf16* __restrict__ vpp, float* __restrict__ O,
    const int* __restrict__ wsz)
{
    const int w  = wsz[0];
    const int w2 = 2 * w;

    // XCD-aware decode: each XCD owns heads {2*xcd, 2*xcd+1}
    const int lin = blockIdx.x;
    const int xcd = lin & 7;
    const int i2  = lin >> 3;            // 0..63
    const int h   = 2 * xcd + (i2 >> 5); // 0..15
    const int q0  = (i2 & 31) * QT;

    const int tid  = threadIdx.x;
    const int lane = tid & 63;
    const int wv   = tid >> 6;
    const int l15  = lane & 15;
    const int g    = lane >> 4;

    const float* Qh = Q + (size_t)h * SEQ * HD;
    float*       Oh = O + (size_t)h * SEQ * HD;

    // Q fragments (B-operand: col=q=l15, k=d=g*8+j); scale into log2 domain
    const float qscale = 0.125f * 1.44269504f;
    bf16x8 qf[2][2];
#pragma unroll
    for (int rb = 0; rb < 2; ++rb)
#pragma unroll
        for (int ks = 0; ks < 2; ++ks) {
            const float* src = Qh + (size_t)(q0 + wv*32 + rb*16 + l15) * HD + ks*32 + g*8;
            float4 a = *(const float4*)src;
            float4 b = *(const float4*)(src + 4);
            bf16x8 t;
            t[0] = (__bf16)(a.x * qscale); t[1] = (__bf16)(a.y * qscale);
            t[2] = (__bf16)(a.z * qscale); t[3] = (__bf16)(a.w * qscale);
            t[4] = (__bf16)(b.x * qscale); t[5] = (__bf16)(b.y * qscale);
            t[6] = (__bf16)(b.z * qscale); t[7] = (__bf16)(b.w * qscale);
            qf[rb][ks] = t;
        }

    f32x4 acc[2][4];
    float lrp[2] = {0.f, 0.f};
#pragma unroll
    for (int rb = 0; rb < 2; ++rb)
#pragma unroll
        for (int db = 0; db < 4; ++db)
            acc[rb][db] = f32x4{0.f, 0.f, 0.f, 0.f};

    // ---- wave-PRIVATE kv range (32 q rows) ----
    const int rw0 = q0 + wv * 32;
    int kv_lo = rw0 - w; if (kv_lo < 0) kv_lo = 0; kv_lo &= ~(KVB - 1);
    int kv_hi = rw0 + 32 + w; if (kv_hi > SEQ) kv_hi = SEQ;
    kv_hi = (kv_hi + KVB - 1) & ~(KVB - 1);
    const int nT = (kv_hi - kv_lo) / KVB;

    const size_t tb0 = ((size_t)h * NTILE + (kv_lo >> 6)) * TILE_U4;
    const uint4* kt = (const uint4*)kpp + tb0;
    const uint4* vt = (const uint4*)vpp + tb0;

    uint4 kC[8], kN[8], vC[8];
#pragma unroll
    for (int f = 0; f < 8; ++f) kC[f] = kt[f * 64 + lane];

    for (int it = 0; it < nT; ++it) {
        const int kb = kv_lo + it * KVB;

        // V for current tile + K for next tile: issued first, consumed late;
        // compiler inserts counted vmcnt on first register use (no drains)
        const uint4* vtp = vt + (size_t)it * TILE_U4;
#pragma unroll
        for (int f = 0; f < 8; ++f) vC[f] = vtp[f * 64 + lane];
        const int itn = (it + 1 < nT) ? (it + 1) : it;
        const uint4* ktn = kt + (size_t)itn * TILE_U4;
#pragma unroll
        for (int f = 0; f < 8; ++f) kN[f] = ktn[f * 64 + lane];

        // ---- S^T = K x Q: st[rb][t][r] = S[key=a(t,g,r)][q = rb-half+l15] ----
        f32x4 st[2][4];
#pragma unroll
        for (int t = 0; t < 4; ++t) {
            bf16x8 kf0 = __builtin_bit_cast(bf16x8, kC[t*2]);
            bf16x8 kf1 = __builtin_bit_cast(bf16x8, kC[t*2+1]);
            f32x4 z0{0.f,0.f,0.f,0.f}, z1{0.f,0.f,0.f,0.f};
            z0       = __builtin_amdgcn_mfma_f32_16x16x32_bf16(kf0, qf[0][0], z0, 0,0,0);
            st[0][t] = __builtin_amdgcn_mfma_f32_16x16x32_bf16(kf1, qf[0][1], z0, 0,0,0);
            z1       = __builtin_amdgcn_mfma_f32_16x16x32_bf16(kf0, qf[1][0], z1, 0,0,0);
            st[1][t] = __builtin_amdgcn_mfma_f32_16x16x32_bf16(kf1, qf[1][1], z1, 0,0,0);
        }

        // ---- mask (fully-masked rows -> p=0 -> contribute nothing) ----
        const bool full = (kb + KVB-1 - rw0 <= w) && (kb - (rw0 + 31) >= -w);
        if (!full) {
#pragma unroll
            for (int rb = 0; rb < 2; ++rb) {
                const int relb = kb + g*8 + w - (rw0 + rb*16) - l15;
#pragma unroll
                for (int t = 0; t < 4; ++t)
#pragma unroll
                    for (int r = 0; r < 4; ++r)
                        if ((unsigned)(relb + (t&1)*32 + (t>>1)*4 + r) > (unsigned)w2)
                            st[rb][t][r] = NEGV;
            }
        }

        // ---- p = exp2(min(s,80)); static softmax; per-lane partial sums ----
        float p[2][4][4];
#pragma unroll
        for (int rb = 0; rb < 2; ++rb) {
#pragma unroll
            for (int t = 0; t < 4; ++t)
#pragma unroll
                for (int r = 0; r < 4; ++r)
                    p[rb][t][r] = __builtin_amdgcn_exp2f(fminf(st[rb][t][r], 80.f));
            float s01 = (p[rb][0][0] + p[rb][0][1]) + (p[rb][0][2] + p[rb][0][3]);
            float s23 = (p[rb][1][0] + p[rb][1][1]) + (p[rb][1][2] + p[rb][1][3]);
            float s45 = (p[rb][2][0] + p[rb][2][1]) + (p[rb][2][2] + p[rb][2][3]);
            float s67 = (p[rb][3][0] + p[rb][3][1]) + (p[rb][3][2] + p[rb][3][3]);
            lrp[rb] += (s01 + s23) + (s45 + s67);
        }

        // ---- PV: pf[rb][kh] = {p[rb][kh][0..3], p[rb][kh+2][0..3]} ----
#pragma unroll
        for (int kh = 0; kh < 2; ++kh) {
            bf16x8 pf0, pf1;
            pf0[0]=(__bf16)p[0][kh][0];   pf0[1]=(__bf16)p[0][kh][1];
            pf0[2]=(__bf16)p[0][kh][2];   pf0[3]=(__bf16)p[0][kh][3];
            pf0[4]=(__bf16)p[0][kh+2][0]; pf0[5]=(__bf16)p[0][kh+2][1];
            pf0[6]=(__bf16)p[0][kh+2][2]; pf0[7]=(__bf16)p[0][kh+2][3];
            pf1[0]=(__bf16)p[1][kh][0];   pf1[1]=(__bf16)p[1][kh][1];
            pf1[2]=(__bf16)p[1][kh][2];   pf1[3]=(__bf16)p[1][kh][3];
            pf1[4]=(__bf16)p[1][kh+2][0]; pf1[5]=(__bf16)p[1][kh+2][1];
            pf1[6]=(__bf16)p[1][kh+2][2]; pf1[7]=(__bf16)p[1][kh+2][3];
#pragma unroll
            for (int db = 0; db < 4; ++db) {
                bf16x8 vfr = __builtin_bit_cast(bf16x8, vC[kh*4 + db]);
                acc[0][db] = __builtin_amdgcn_mfma_f32_16x16x32_bf16(pf0, vfr, acc[0][db], 0,0,0);
                acc[1][db] = __builtin_amdgcn_mfma_f32_16x16x32_bf16(pf1, vfr, acc[1][db], 0,0,0);
            }
        }

        // rotate K double-buffer
#pragma unroll
        for (int f = 0; f < 8; ++f) kC[f] = kN[f];
    }

    // ---- epilogue: g-reduce l, normalize, store ----
#pragma unroll
    for (int rb = 0; rb < 2; ++rb) {
        float lr = lrp[rb];
        lr += __shfl_xor(lr, 16);
        lr += __shfl_xor(lr, 32);
        const float il = 1.0f / lr;
        float inv[4];
#pragma unroll
        for (int r = 0; r < 4; ++r) inv[r] = __shfl(il, g*4 + r);
#pragma unroll
        for (int db = 0; db < 4; ++db)
#pragma unroll
            for (int r = 0; r < 4; ++r) {
                const int row = rw0 + rb*16 + g*4 + r;
                Oh[(size_t)row * HD + db*16 + l15] = acc[rb][db][r] * inv[r];
            }
    }
}

// ===================== fallback (R10, fp32-staged, QT=128) =================
__device__ __forceinline__ int prow_of(int key) {
    return ((key >> 2) & 1) * 32 + ((key >> 5) & 1) * 16
         + ((key >> 3) & 3) * 4  + (key & 3);
}
__global__ __launch_bounds__(512) void swa_fwd_fb(
    const float* __restrict__ Q, const float* __restrict__ K,
    const float* __restrict__ V, float* __restrict__ O,
    const int* __restrict__ wsz)
{
    const int w    = wsz[0];
    const int w2   = 2 * w;
    const int lin = blockIdx.x;
    const int xcd = lin & 7;
    const int i2  = lin >> 3;
    const int h   = 2 * xcd + (i2 >> 6);
    const int q0  = (i2 & 63) * 128;
    const int tid  = threadIdx.x;
    const int lane = tid & 63;
    const int wv   = tid >> 6;
    const int l15  = lane & 15;
    const int g    = lane >> 4;
    const size_t hoff = (size_t)h * SEQ * HD;
    const float* Qh = Q + hoff;
    const float* Kh = K + hoff;
    const float* Vh = V + hoff;
    float*       Oh = O + hoff;
    __shared__ __align__(16) __bf16 Ks[2][KVB * 64];
    __shared__ __align__(16) __bf16 Vt[2][64 * 64];
    const float qscale = 0.125f * 1.44269504f;
    const int   qrow   = q0 + wv * 16 + l15;
    bf16x8 qf[2];
#pragma unroll
    for (int ks = 0; ks < 2; ++ks) {
        const float* src = Qh + (size_t)qrow * HD + ks*32 + g*8;
        float4 a = *(const float4*)src;
        float4 b = *(const float4*)(src + 4);
        bf16x8 t;
        t[0] = (__bf16)(a.x * qscale); t[1] = (__bf16)(a.y * qscale);
        t[2] = (__bf16)(a.z * qscale); t[3] = (__bf16)(a.w * qscale);
        t[4] = (__bf16)(b.x * qscale); t[5] = (__bf16)(b.y * qscale);
        t[6] = (__bf16)(b.z * qscale); t[7] = (__bf16)(b.w * qscale);
        qf[ks] = t;
    }
    f32x4 acc[4];
    float lrp = 0.f;
#pragma unroll
    for (int db = 0; db < 4; ++db) acc[db] = f32x4{0.f, 0.f, 0.f, 0.f};
    int kv_lo = q0 - w; if (kv_lo < 0) kv_lo = 0; kv_lo &= ~(KVB - 1);
    int kv_hi = q0 + 128 + w; if (kv_hi > SEQ) kv_hi = SEQ;
    kv_hi = (kv_hi + KVB - 1) & ~(KVB - 1);
    const int nT = (kv_hi - kv_lo) / KVB;
    const int rw0 = q0 + wv * 16;
    const int kkey = tid >> 3, kd8 = (tid & 7) * 8;
    const int prow = prow_of(kkey);
    const int swk  = (prow & 7) << 3;
    const int vd   = tid & 63, vk0 = (tid >> 6) * 8;
    const int swv  = (vd & 7) << 3;
    float4 kpa, kpb;
    float  vp[8];
#define ISSUE_LOADS_FB(KB)                                                     \
    {                                                                          \
        const float* ksrc = Kh + (size_t)((KB) + kkey) * HD + kd8;             \
        kpa = *(const float4*)ksrc;                                            \
        kpb = *(const float4*)(ksrc + 4);                                      \
        const float* vsrc = Vh + (size_t)((KB) + vk0) * HD + vd;               \
        _Pragma("unroll")                                                      \
        for (int j = 0; j < 8; ++j) vp[j] = vsrc[j * HD];                      \
    }
#define CVT_STORE_FB(BUF)                                                      \
    {                                                                          \
        bf16x8 tk;                                                             \
        tk[0] = (__bf16)kpa.x; tk[1] = (__bf16)kpa.y;                          \
        tk[2] = (__bf16)kpa.z; tk[3] = (__bf16)kpa.w;                          \
        tk[4] = (__bf16)kpb.x; tk[5] = (__bf16)kpb.y;                          \
        tk[6] = (__bf16)kpb.z; tk[7] = (__bf16)kpb.w;                          \
        *(bf16x8*)&Ks[BUF][prow*64 + (kd8 ^ swk)] = tk;                        \
        bf16x8 tv;                                                             \
        _Pragma("unroll")                                                      \
        for (int j = 0; j < 8; ++j) tv[j] = (__bf16)vp[j];                     \
        *(bf16x8*)&Vt[BUF][vd*64 + (vk0 ^ swv)] = tv;                          \
    }
#define WG_BARRIER_FB()                                                        \
    asm volatile("s_waitcnt lgkmcnt(0)" ::: "memory");                         \
    __builtin_amdgcn_sched_barrier(0);                                         \
    __builtin_amdgcn_s_barrier();                                              \
    __builtin_amdgcn_sched_barrier(0);
    ISSUE_LOADS_FB(kv_lo);
    CVT_STORE_FB(0);
    if (nT > 1) ISSUE_LOADS_FB(kv_lo + KVB);
    WG_BARRIER_FB();
    for (int it = 0; it < nT; ++it) {
        const int kb = kv_lo + it * KVB;
        const __bf16* Kb = &Ks[it & 1][0];
        const __bf16* Vb = &Vt[it & 1][0];
        if (kb <= rw0 + 15 + w && kb + KVB - 1 >= rw0 - w) {
            const int sw = (l15 & 7) << 3;
            f32x4 st[4];
#pragma unroll
            for (int t = 0; t < 4; ++t) {
                bf16x8 kf0 = *(const bf16x8*)&Kb[(t*16 + l15)*64 + ((     g*8) ^ sw)];
                bf16x8 kf1 = *(const bf16x8*)&Kb[(t*16 + l15)*64 + ((32 + g*8) ^ sw)];
                f32x4 z{0.f, 0.f, 0.f, 0.f};
                z     = __builtin_amdgcn_mfma_f32_16x16x32_bf16(kf0, qf[0], z, 0,0,0);
                st[t] = __builtin_amdgcn_mfma_f32_16x16x32_bf16(kf1, qf[1], z, 0,0,0);
            }
            const bool full = (kb + KVB-1 - rw0 <= w) && (kb - (rw0 + 15) >= -w);
            if (!full) {
                const int relb = kb + g*8 + w - rw0 - l15;
#pragma unroll
                for (int t = 0; t < 4; ++t)
#pragma unroll
                    for (int r = 0; r < 4; ++r)
                        if ((unsigned)(relb + (t&1)*32 + (t>>1)*4 + r) > (unsigned)w2)
                            st[t][r] = NEGV;
            }
            float p[4][4];
#pragma unroll
            for (int t = 0; t < 4; ++t)
#pragma unroll
                for (int r = 0; r < 4; ++r)
                    p[t][r] = __builtin_amdgcn_exp2f(fminf(st[t][r], 80.f));
            float s01 = (p[0][0] + p[0][1]) + (p[0][2] + p[0][3]);
            float s23 = (p[1][0] + p[1][1]) + (p[1][2] + p[1][3]);
            float s45 = (p[2][0] + p[2][1]) + (p[2][2] + p[2][3]);
            float s67 = (p[3][0] + p[3][1]) + (p[3][2] + p[3][3]);
            lrp += (s01 + s23) + (s45 + s67);
#pragma unroll
            for (int kh = 0; kh < 2; ++kh) {
                bf16x8 pf;
                pf[0] = (__bf16)p[kh][0];   pf[1] = (__bf16)p[kh][1];
                pf[2] = (__bf16)p[kh][2];   pf[3] = (__bf16)p[kh][3];
                pf[4] = (__bf16)p[kh+2][0]; pf[5] = (__bf16)p[kh+2][1];
                pf[6] = (__bf16)p[kh+2][2]; pf[7] = (__bf16)p[kh+2][3];
#pragma unroll
                for (int db = 0; db < 4; ++db) {
                    bf16x8 vfr = *(const bf16x8*)&Vb[(db*16 + l15)*64 + ((kh*32 + g*8) ^ sw)];
                    acc[db] = __builtin_amdgcn_mfma_f32_16x16x32_bf16(pf, vfr, acc[db], 0,0,0);
                }
            }
        }
        if (it + 1 < nT) {
            CVT_STORE_FB((it + 1) & 1);
            if (it + 2 < nT) ISSUE_LOADS_FB(kb + 2 * KVB);
        }
        WG_BARRIER_FB();
    }
    float lr = lrp;
    lr += __shfl_xor(lr, 16);
    lr += __shfl_xor(lr, 32);
    const float il = 1.0f / lr;
    float inv[4];
#pragma unroll
    for (int r = 0; r < 4; ++r) inv[r] = __shfl(il, g*4 + r);
#pragma unroll
    for (int db = 0; db < 4; ++db)
#pragma unroll
        for (int r = 0; r < 4; ++r) {
            const int row = rw0 + g*4 + r;
            Oh[(size_t)row * HD + db*16 + l15] = acc[db][r] * inv[r];
        }
}

extern "C" void kernel_launch(void* const* d_in, const int* in_sizes, int n_in,
                              void* d_out, int out_size, void* d_ws, size_t ws_size,
                              hipStream_t stream) {
    const float* Q   = (const float*)d_in[0];
    const float* K   = (const float*)d_in[1];
    const float* V   = (const float*)d_in[2];
    const int*   wsz = (const int*)d_in[4];   // window_size (d_in[3]=batch_size unused)
    float* O = (float*)d_out;

    const size_t imgBytes = (size_t)NH * NTILE * TILE_ELEMS * sizeof(__bf16); // 16.78MB
    if (ws_size >= 2 * imgBytes) {
        __bf16* kpp = (__bf16*)d_ws;
        __bf16* vpp = (__bf16*)((char*)d_ws + imgBytes);
        prepack<<<dim3(2 * NH * NTILE), dim3(512), 0, stream>>>(K, V, kpp, vpp);
        swa_fwd<<<dim3((SEQ / QT) * NH), dim3(512), 0, stream>>>(Q, kpp, vpp, O, wsz);
    } else {
        swa_fwd_fb<<<dim3((SEQ / 128) * NH), dim3(512), 0, stream>>>(Q, K, V, O, wsz);
    }
}